// Round 1
// 465.209 us; speedup vs baseline: 1.0157x; 1.0157x over previous
//
#include <hip/hip_runtime.h>

#define NL     8
#define DD     64
#define HIN    8192
#define HIDN   4096
#define MM     512
#define SPLITS 4

using frag8 = __attribute__((ext_vector_type(8))) short;   // 8 bf16 (4 VGPRs)
using f32x4 = __attribute__((ext_vector_type(4))) float;
using s16x4 = __attribute__((ext_vector_type(4))) short;

#define MFMA16(a, b, c) __builtin_amdgcn_mfma_f32_16x16x32_bf16((a), (b), (c), 0, 0, 0)

// global -> LDS direct DMA, 16 B per lane. LDS dest = wave-uniform base + lane*16.
#define GLL16(g, l)                                                            \
  __builtin_amdgcn_global_load_lds(                                            \
      (const __attribute__((address_space(1))) void*)(g),                      \
      (__attribute__((address_space(3))) void*)(l), 16, 0, 0)

static __device__ __forceinline__ float bf2f(unsigned short h) {
  union { unsigned u; float f; } c; c.u = ((unsigned)h) << 16; return c.f;
}
static __device__ __forceinline__ unsigned short f2bf(float f) {
  union { float f; unsigned u; } c; c.f = f;
  unsigned u = c.u + 0x7FFFu + ((c.u >> 16) & 1u);   // RNE
  return (unsigned short)(u >> 16);
}
static __device__ __forceinline__ void split2(float v, short& hi, short& lo) {
  unsigned short h = f2bf(v);
  hi = (short)h;
  lo = (short)f2bf(v - bf2f(h));
}
// convert 8 fp32 (already in regs) -> hi/lo bf16 frags
static __device__ __forceinline__ void conv_split(const float4 v0, const float4 v1,
                                                  frag8& hi, frag8& lo) {
  float vv[8] = {v0.x, v0.y, v0.z, v0.w, v1.x, v1.y, v1.z, v1.w};
  _Pragma("unroll")
  for (int t = 0; t < 8; ++t) {
    unsigned short h = f2bf(vv[t]);
    hi[t] = (short)h;
    lo[t] = (short)f2bf(vv[t] - bf2f(h));
  }
}

static __device__ __forceinline__ float mish_f(float x) {
  float e  = __expf(x);
  float sp = (x > 15.f) ? x : __logf(1.f + e);      // softplus, stable for huge |x|
  float em = __expf(-2.f * sp);
  float t  = (1.f - em) / (1.f + em);               // tanh(sp), sp>=0
  return x * t;
}

// pack 8 fp32 -> 8 bf16 (RTZ truncation) via v_perm_b32, 1 instr / 2 elems
static __device__ __forceinline__ frag8 pack8(f32x4 a, f32x4 b) {
  union { frag8 f; unsigned u[4]; } r;
  r.u[0] = __builtin_amdgcn_perm(__float_as_uint(a[1]), __float_as_uint(a[0]), 0x07060302u);
  r.u[1] = __builtin_amdgcn_perm(__float_as_uint(a[3]), __float_as_uint(a[2]), 0x07060302u);
  r.u[2] = __builtin_amdgcn_perm(__float_as_uint(b[1]), __float_as_uint(b[0]), 0x07060302u);
  r.u[3] = __builtin_amdgcn_perm(__float_as_uint(b[3]), __float_as_uint(b[2]), 0x07060302u);
  return r.f;
}

// ---------------------------------------------------------------------------
// Pre-split W (8 x 64 x 64 complex) into bf16 hi/lo once (was re-split by all
// 512 chain blocks). Layout: Wsp = [rh | rl | ih | il], each NL*DD*DD shorts.
// ---------------------------------------------------------------------------
__global__ __launch_bounds__(256) void w_split_kernel(
    const float* __restrict__ W_r, const float* __restrict__ W_i,
    unsigned short* __restrict__ Wsp)
{
  const int idx = blockIdx.x * 256 + threadIdx.x;   // < NL*DD*DD = 32768
  short h, l;
  split2(W_r[idx], h, l);
  Wsp[idx]             = (unsigned short)h;
  Wsp[32768 + idx]     = (unsigned short)l;
  split2(W_i[idx], h, l);
  Wsp[2 * 32768 + idx] = (unsigned short)h;
  Wsp[3 * 32768 + idx] = (unsigned short)l;
}

// ---------------------------------------------------------------------------
// Kernel 1: per-batch matrix chain  out = u - W7 x7 W6 x6 ... W0 x0
// v2: double-buffered LDS (1 barrier/phase, was 2), register-prefetched
// A-operand (x raw floats / pre-split W frags loaded one phase ahead),
// XOR-swizzled unpadded [64][64] LDS (64 KB total -> 2 blocks/CU).
// idx(row, col) = row*64 + (col ^ ((row&7)*8))  -- swizzle on 8-short slots.
// ---------------------------------------------------------------------------
#define LOAD_WF(lyr) do {                                                      \
  _Pragma("unroll") for (int kc_ = 0; kc_ < 2; ++kc_) {                        \
    const int aoff = (lyr) * (DD * DD) + (mrow + l16) * 64 + kc_ * 32 + quad * 8; \
    wf[kc_][0] = *(const frag8*)&Wrh[aoff];                                    \
    wf[kc_][1] = *(const frag8*)&Wrl[aoff];                                    \
    wf[kc_][2] = *(const frag8*)&Wih[aoff];                                    \
    wf[kc_][3] = *(const frag8*)&Wil[aoff];                                    \
  }                                                                            \
} while (0)

#define PREFETCH_X(lyr) do {                                                   \
  const float* xr_ = x_r + ((size_t)b * NL + (lyr)) * (DD * DD);               \
  const float* xi_ = x_i + ((size_t)b * NL + (lyr)) * (DD * DD);               \
  _Pragma("unroll") for (int kc_ = 0; kc_ < 2; ++kc_) {                        \
    const int aoff = (mrow + l16) * 64 + kc_ * 32 + quad * 8;                  \
    xr4[kc_][0] = *(const float4*)(xr_ + aoff);                                \
    xr4[kc_][1] = *(const float4*)(xr_ + aoff + 4);                            \
    xr4[kc_][2] = *(const float4*)(xi_ + aoff);                                \
    xr4[kc_][3] = *(const float4*)(xi_ + aoff + 4);                            \
  }                                                                            \
} while (0)

#define CONV_X() do {                                                          \
  _Pragma("unroll") for (int kc_ = 0; kc_ < 2; ++kc_) {                        \
    conv_split(xr4[kc_][0], xr4[kc_][1], xf[kc_][0], xf[kc_][1]);              \
    conv_split(xr4[kc_][2], xr4[kc_][3], xf[kc_][2], xf[kc_][3]);              \
  }                                                                            \
} while (0)

#define CMM_FR(f, rb) do {                                                     \
  _Pragma("unroll") for (int c = 0; c < 4; ++c) { accr[c] = zero4; acci[c] = zero4; } \
  _Pragma("unroll") for (int kc = 0; kc < 2; ++kc) {                           \
    const int k0 = kc * 32 + quad * 8;                                         \
    const frag8 arh = f[kc][0], arl = f[kc][1];                                \
    const frag8 aih = f[kc][2], ail = f[kc][3];                                \
    const frag8 aihn = aih ^ (short)0x8000;                                    \
    const frag8 ailn = ail ^ (short)0x8000;                                    \
    _Pragma("unroll") for (int c = 0; c < 4; ++c) {                            \
      const int bi = (c * 16 + l16) * 64 + (k0 ^ ((l16 & 7) * 8));             \
      frag8 brh = *(const frag8*)&B_rh[rb][bi];                                \
      frag8 brl = *(const frag8*)&B_rl[rb][bi];                                \
      frag8 bih = *(const frag8*)&B_ih[rb][bi];                                \
      frag8 bil = *(const frag8*)&B_il[rb][bi];                                \
      accr[c] = MFMA16(arh,  brh, accr[c]);                                    \
      accr[c] = MFMA16(arh,  brl, accr[c]);                                    \
      accr[c] = MFMA16(arl,  brh, accr[c]);                                    \
      accr[c] = MFMA16(aihn, bih, accr[c]);                                    \
      accr[c] = MFMA16(aihn, bil, accr[c]);                                    \
      accr[c] = MFMA16(ailn, bih, accr[c]);                                    \
      acci[c] = MFMA16(arh,  bih, acci[c]);                                    \
      acci[c] = MFMA16(arh,  bil, acci[c]);                                    \
      acci[c] = MFMA16(arl,  bih, acci[c]);                                    \
      acci[c] = MFMA16(aih,  brh, acci[c]);                                    \
      acci[c] = MFMA16(aih,  brl, acci[c]);                                    \
      acci[c] = MFMA16(ail,  brh, acci[c]);                                    \
    }                                                                          \
  }                                                                            \
} while (0)

#define WRITE_BT(wb) do {                                                      \
  _Pragma("unroll") for (int c = 0; c < 4; ++c) {                              \
    const int wi = (c * 16 + l16) * 64 + ((mrow + quad * 4) ^ ((l16 & 7) * 8)); \
    s16x4 rh, rl, ih, il;                                                      \
    _Pragma("unroll") for (int g = 0; g < 4; ++g) {                            \
      short h_, l_;                                                            \
      split2(accr[c][g], h_, l_); rh[g] = h_; rl[g] = l_;                      \
      split2(acci[c][g], h_, l_); ih[g] = h_; il[g] = l_;                      \
    }                                                                          \
    *(s16x4*)&B_rh[wb][wi] = rh;                                               \
    *(s16x4*)&B_rl[wb][wi] = rl;                                               \
    *(s16x4*)&B_ih[wb][wi] = ih;                                               \
    *(s16x4*)&B_il[wb][wi] = il;                                               \
  }                                                                            \
} while (0)

__global__ __launch_bounds__(256, 2) void chain_kernel(
    const float* __restrict__ x_r, const float* __restrict__ x_i,
    const float* __restrict__ u_r, const float* __restrict__ u_i,
    const unsigned short* __restrict__ Wsp,
    unsigned short* __restrict__ feat)
{
  __shared__ short B_rh[2][DD * DD];    // 4 arrays x 2 bufs x 8 KB = 64 KB
  __shared__ short B_rl[2][DD * DD];
  __shared__ short B_ih[2][DD * DD];
  __shared__ short B_il[2][DD * DD];

  const int tid  = threadIdx.x;
  const int b    = blockIdx.x;
  const int lane = tid & 63;
  const int quad = lane >> 4;
  const int l16  = lane & 15;
  const int mrow = (tid >> 6) * 16;
  const f32x4 zero4 = {0.f, 0.f, 0.f, 0.f};
  f32x4 accr[4], acci[4];

  const short* Wrh = (const short*)Wsp;
  const short* Wrl = Wrh + NL * DD * DD;
  const short* Wih = Wrl + NL * DD * DD;
  const short* Wil = Wih + NL * DD * DD;

  frag8  wf[2][4];    // next W-phase fragments (prefetched)
  float4 xr4[2][4];   // next x-phase raw floats (prefetched)
  frag8  xf[2][4];    // converted x fragments (phase-local)

  // stage x0 transposed into buf 0
  {
    const float* xr0 = x_r + (size_t)b * (NL * DD * DD);
    const float* xi0 = x_i + (size_t)b * (NL * DD * DD);
    _Pragma("unroll")
    for (int j = 0; j < 16; ++j) {
      const int idx = j * 256 + tid;
      const int q = idx >> 6, r = idx & 63;
      const int w = r * 64 + (q ^ ((r & 7) * 8));
      short h_, l_;
      split2(xr0[idx], h_, l_); B_rh[0][w] = h_; B_rl[0][w] = l_;
      split2(xi0[idx], h_, l_); B_ih[0][w] = h_; B_il[0][w] = l_;
    }
  }
  LOAD_WF(0);          // prologue: W0 fragments (latency paid once)
  __syncthreads();

  int pb = 0;
  _Pragma("unroll 1")
  for (int step = 0; step < 7; ++step) {
    // phase A: tmp = W[step] * out    (reads buf pb, writes pb^1)
    PREFETCH_X(step + 1);             // issue x loads; land during MFMAs
    CMM_FR(wf, pb);
    WRITE_BT(pb ^ 1);
    __syncthreads();
    pb ^= 1;
    // phase B: out = x[step+1] * tmp
    CONV_X();                         // x floats arrived one phase ago
    LOAD_WF(step + 1);                // issue next W frag loads
    CMM_FR(xf, pb);
    WRITE_BT(pb ^ 1);
    __syncthreads();
    pb ^= 1;
  }
  // final: acc = W7 * out
  CMM_FR(wf, pb);

  const float* ur = u_r + (size_t)b * (DD * DD);
  const float* ui = u_i + (size_t)b * (DD * DD);
  unsigned short* fb = feat + (size_t)b * HIN;
  _Pragma("unroll")
  for (int c = 0; c < 4; ++c) {
    _Pragma("unroll")
    for (int g = 0; g < 4; ++g) {
      const int p = mrow + quad * 4 + g;
      const int r = c * 16 + l16;
      fb[p * 128 + r]      = f2bf(ur[p * 64 + r] - accr[c][g]);
      fb[p * 128 + 64 + r] = f2bf(ui[p * 64 + r] - acci[c][g]);
    }
  }
}

// ---------------------------------------------------------------------------
// Split-K GEMM, v2: always S=4 (512 blocks, 2/CU) with device-scope fp32
// atomicAdd into a SINGLE part buffer (same footprint as old S=1 path).
// part[m][n] += sum_{k in split s} A[m][k] * Wg[n][k]
// Tile 128(m) x 128(n), BK = 64, 4 waves (2x2). XCD-grouped decode kept so
// the 4 m-tile blocks sharing a Wg stripe stay L2-local.
// ---------------------------------------------------------------------------
__global__ __launch_bounds__(256, 2) void gemm_splitk_kernel(
    const unsigned short* __restrict__ A,
    const float* __restrict__ Wg,
    float* __restrict__ part,
    const int K, const int S)
{
  __shared__ __align__(16) short As[128 * 64];   // 16 KB, idx = r*64 + (c ^ ((r&7)*8))
  __shared__ __align__(16) float Bs[128 * 64];   // 32 KB, idx = r*64 + 4*((c>>2) ^ (r&7)) + (c&3)

  const int tid = threadIdx.x;
  const int bx  = blockIdx.x;
  // decode: xcd = bx&7; j = bx>>3 = m + 4*(s + S*n_sub)  (m fastest => same-B blocks adjacent)
  const int jj     = bx >> 3;
  const int m_tile = jj & 3;
  const int t2     = jj >> 2;
  const int s      = t2 % S;
  const int n_sub  = t2 / S;
  const int n_tile = (bx & 7) * 4 + n_sub;
  const int m0 = m_tile * 128, n0 = n_tile * 128;
  const int kPer  = K / S;
  const int kBase = s * kPer;

  const int wv = tid >> 6, lane = tid & 63;
  const int quad = lane >> 4, l16 = lane & 15;
  const int wm = wv & 1, wn = wv >> 1;

  // --- staging address precompute -----------------------------------------
  const int arow_loc = lane >> 3;
  const int acol     = ((lane & 7) ^ arow_loc) * 8;
  const unsigned short* aG[4];
  short* aL[4];
  _Pragma("unroll")
  for (int t = 0; t < 4; ++t) {
    const int r = 32 * wv + 8 * t + arow_loc;
    aG[t] = A + (size_t)(m0 + r) * K + kBase + acol;
    aL[t] = &As[(32 * wv + 8 * t) * 64];
  }
  const int brow_loc = lane >> 4;
  const float* bG[8];
  float* bL[8];
  _Pragma("unroll")
  for (int t = 0; t < 8; ++t) {
    const int r  = 32 * wv + 4 * t + brow_loc;
    const int cg = (lane & 15) ^ (r & 7);
    bG[t] = Wg + (size_t)(n0 + r) * K + kBase + cg * 4;
    bL[t] = &Bs[(32 * wv + 4 * t) * 64];
  }

  const f32x4 zero4 = {0.f, 0.f, 0.f, 0.f};
  f32x4 acc[4][4];
  _Pragma("unroll")
  for (int i = 0; i < 4; ++i)
    _Pragma("unroll")
    for (int j = 0; j < 4; ++j) acc[i][j] = zero4;

  const int kIters = kPer >> 6;
  for (int kt = 0; kt < kIters; ++kt) {
    __syncthreads();                       // previous iter's LDS reads done
    _Pragma("unroll")
    for (int t = 0; t < 4; ++t) { GLL16(aG[t], aL[t]); aG[t] += 64; }
    _Pragma("unroll")
    for (int t = 0; t < 8; ++t) { GLL16(bG[t], bL[t]); bG[t] += 64; }
    __syncthreads();                       // staging visible (vmcnt drained)

    _Pragma("unroll")
    for (int kc = 0; kc < 2; ++kc) {
      const int k0 = kc * 32 + quad * 8;
      frag8 af[4];
      _Pragma("unroll")
      for (int i = 0; i < 4; ++i) {
        const int r = wm * 64 + i * 16 + l16;        // r&7 == l16&7
        af[i] = *(const frag8*)&As[r * 64 + (k0 ^ ((l16 & 7) * 8))];
      }
      _Pragma("unroll")
      for (int j = 0; j < 4; ++j) {
        const int r    = wn * 64 + j * 16 + l16;
        const int base = r * 64;
        const int swz  = l16 & 7;
        const int cg0  = k0 >> 2;                    // even
        f32x4 f0 = *(const f32x4*)&Bs[base + 4 * (cg0 ^ swz)];
        f32x4 f1 = *(const f32x4*)&Bs[base + 4 * ((cg0 + 1) ^ swz)];
        frag8 bf = pack8(f0, f1);
        _Pragma("unroll")
        for (int i = 0; i < 4; ++i) acc[i][j] = MFMA16(af[i], bf, acc[i][j]);
      }
    }
  }

  // accumulate fp32 partials into the single part buffer (device-scope atomics)
  _Pragma("unroll")
  for (int i = 0; i < 4; ++i) {
    _Pragma("unroll")
    for (int j = 0; j < 4; ++j) {
      const int n = n0 + wn * 64 + j * 16 + l16;
      _Pragma("unroll")
      for (int g = 0; g < 4; ++g) {
        const int m = m0 + wm * 64 + i * 16 + quad * 4 + g;
        atomicAdd(&part[(size_t)m * HIDN + n], acc[i][j][g]);
      }
    }
  }
}

// ---------------------------------------------------------------------------
// Zero the partial buffer (runs once per launch, ~1.5 us)
// ---------------------------------------------------------------------------
__global__ __launch_bounds__(256) void zero_kernel(float* __restrict__ p) {
  const int idx4 = (blockIdx.x * 256 + threadIdx.x) * 4;
  const f32x4 z = {0.f, 0.f, 0.f, 0.f};
  *(f32x4*)&p[idx4] = z;
}

// ---------------------------------------------------------------------------
// bias + mish -> bf16, and re-zero part for the next GEMM (free-ish store)
// ---------------------------------------------------------------------------
__global__ __launch_bounds__(256) void reduce_mish_kernel(
    float* __restrict__ part, const float* __restrict__ bias,
    unsigned short* __restrict__ outp)
{
  const int idx4 = (blockIdx.x * 256 + threadIdx.x) * 4;   // < 512*4096
  const int n = idx4 & (HIDN - 1);
  f32x4 acc = *(const f32x4*)&part[idx4];
  const f32x4 z = {0.f, 0.f, 0.f, 0.f};
  *(f32x4*)&part[idx4] = z;
  const f32x4 bv = *(const f32x4*)&bias[n];
  s16x4 o;
  _Pragma("unroll")
  for (int g = 0; g < 4; ++g) o[g] = (short)f2bf(mish_f(acc[g] + bv[g]));
  *(s16x4*)&outp[idx4] = o;
}

// ---------------------------------------------------------------------------
// Final gemv: out[b] = sum_k h2[b][k]*w3[k] + b3
// ---------------------------------------------------------------------------
__global__ __launch_bounds__(256) void gemv_kernel(
    const unsigned short* __restrict__ h2,
    const float* __restrict__ w3,
    const float* __restrict__ b3,
    float* __restrict__ outp)
{
  const int gw   = (int)((blockIdx.x * 256 + threadIdx.x) >> 6);
  const int lane = threadIdx.x & 63;
  const unsigned short* hp = h2 + (size_t)gw * HIDN;
  float s = 0.f;
  for (int j = 0; j < 16; ++j) {
    const int k = j * 256 + lane * 4;
    const s16x4 h = *(const s16x4*)(hp + k);
    const float4 w = *(const float4*)(w3 + k);
    s += bf2f((unsigned short)h[0]) * w.x + bf2f((unsigned short)h[1]) * w.y
       + bf2f((unsigned short)h[2]) * w.z + bf2f((unsigned short)h[3]) * w.w;
  }
  _Pragma("unroll")
  for (int off = 32; off > 0; off >>= 1) s += __shfl_down(s, off, 64);
  if (lane == 0) outp[gw] = s + b3[0];
}

extern "C" void kernel_launch(void* const* d_in, const int* in_sizes, int n_in,
                              void* d_out, int out_size, void* d_ws, size_t ws_size,
                              hipStream_t stream) {
  const float* x_r = (const float*)d_in[0];
  const float* x_i = (const float*)d_in[1];
  const float* u_r = (const float*)d_in[2];
  const float* u_i = (const float*)d_in[3];
  const float* W_r = (const float*)d_in[4];
  const float* W_i = (const float*)d_in[5];
  const float* w1  = (const float*)d_in[6];
  const float* b1  = (const float*)d_in[7];
  const float* w2  = (const float*)d_in[8];
  const float* b2  = (const float*)d_in[9];
  const float* w3  = (const float*)d_in[10];
  const float* b3  = (const float*)d_in[11];
  float* out = (float*)d_out;

  unsigned short* feat = (unsigned short*)d_ws;             // 512*8192 bf16 = 8 MB
  unsigned short* h1   = feat + (size_t)MM * HIN;           // 4 MB
  unsigned short* h2   = h1 + (size_t)MM * HIDN;            // 4 MB
  float* part = (float*)(h2 + (size_t)MM * HIDN);           // 8.39 MB fp32 (single)
  unsigned short* Wsp = h1;   // W hi/lo split lives in h1 region (256 KB),
                              // dead before reduce_mish writes h1

  w_split_kernel<<<128, 256, 0, stream>>>(W_r, W_i, Wsp);
  zero_kernel<<<2048, 256, 0, stream>>>(part);
  chain_kernel<<<512, 256, 0, stream>>>(x_r, x_i, u_r, u_i, Wsp, feat);
  gemm_splitk_kernel<<<128 * SPLITS, 256, 0, stream>>>(feat, w1, part, HIN, SPLITS);
  reduce_mish_kernel<<<2048, 256, 0, stream>>>(part, b1, h1);
  gemm_splitk_kernel<<<128 * SPLITS, 256, 0, stream>>>(h1, w2, part, HIDN, SPLITS);
  reduce_mish_kernel<<<2048, 256, 0, stream>>>(part, b2, h2);
  gemv_kernel<<<128, 256, 0, stream>>>(h2, w3, b3, out);
}

// Round 2
// 462.224 us; speedup vs baseline: 1.0223x; 1.0065x over previous
//
#include <hip/hip_runtime.h>

#define NL     8
#define DD     64
#define HIN    8192
#define HIDN   4096
#define MM     512
#define SPLITS 4

using frag8 = __attribute__((ext_vector_type(8))) short;   // 8 bf16 (4 VGPRs)
using f32x4 = __attribute__((ext_vector_type(4))) float;
using s16x4 = __attribute__((ext_vector_type(4))) short;

#define MFMA16(a, b, c) __builtin_amdgcn_mfma_f32_16x16x32_bf16((a), (b), (c), 0, 0, 0)

// global -> LDS direct DMA, 16 B per lane. LDS dest = wave-uniform base + lane*16.
#define GLL16(g, l)                                                            \
  __builtin_amdgcn_global_load_lds(                                            \
      (const __attribute__((address_space(1))) void*)(g),                      \
      (__attribute__((address_space(3))) void*)(l), 16, 0, 0)

// pipelining fences (rule #18: sched_barrier after inline-asm waits/barriers)
#define VMW(n) do { asm volatile("s_waitcnt vmcnt(" #n ")" ::: "memory");      \
                    __builtin_amdgcn_sched_barrier(0); } while (0)
#define LGW()  do { asm volatile("s_waitcnt lgkmcnt(0)" ::: "memory");         \
                    __builtin_amdgcn_sched_barrier(0); } while (0)
#define BAR()  do { __builtin_amdgcn_s_barrier();                              \
                    __builtin_amdgcn_sched_barrier(0); } while (0)

static __device__ __forceinline__ float bf2f(unsigned short h) {
  union { unsigned u; float f; } c; c.u = ((unsigned)h) << 16; return c.f;
}
static __device__ __forceinline__ unsigned short f2bf(float f) {
  union { float f; unsigned u; } c; c.f = f;
  unsigned u = c.u + 0x7FFFu + ((c.u >> 16) & 1u);   // RNE
  return (unsigned short)(u >> 16);
}
static __device__ __forceinline__ void split2(float v, short& hi, short& lo) {
  unsigned short h = f2bf(v);
  hi = (short)h;
  lo = (short)f2bf(v - bf2f(h));
}
// convert 8 fp32 (already in regs) -> hi/lo bf16 frags
static __device__ __forceinline__ void conv_split(const float4 v0, const float4 v1,
                                                  frag8& hi, frag8& lo) {
  float vv[8] = {v0.x, v0.y, v0.z, v0.w, v1.x, v1.y, v1.z, v1.w};
  _Pragma("unroll")
  for (int t = 0; t < 8; ++t) {
    unsigned short h = f2bf(vv[t]);
    hi[t] = (short)h;
    lo[t] = (short)f2bf(vv[t] - bf2f(h));
  }
}

static __device__ __forceinline__ float mish_f(float x) {
  float e  = __expf(x);
  float sp = (x > 15.f) ? x : __logf(1.f + e);      // softplus, stable for huge |x|
  float em = __expf(-2.f * sp);
  float t  = (1.f - em) / (1.f + em);               // tanh(sp), sp>=0
  return x * t;
}

// ---------------------------------------------------------------------------
// Pre-split W (8 x 64 x 64 complex) into bf16 hi/lo once.
// Layout: Wsp = [rh | rl | ih | il], each NL*DD*DD shorts.
// ---------------------------------------------------------------------------
__global__ __launch_bounds__(256) void w_split_kernel(
    const float* __restrict__ W_r, const float* __restrict__ W_i,
    unsigned short* __restrict__ Wsp)
{
  const int idx = blockIdx.x * 256 + threadIdx.x;   // < NL*DD*DD = 32768
  short h, l;
  split2(W_r[idx], h, l);
  Wsp[idx]             = (unsigned short)h;
  Wsp[32768 + idx]     = (unsigned short)l;
  split2(W_i[idx], h, l);
  Wsp[2 * 32768 + idx] = (unsigned short)h;
  Wsp[3 * 32768 + idx] = (unsigned short)l;
}

// ---------------------------------------------------------------------------
// Kernel 1: per-batch matrix chain  out = u - W7 x7 W6 x6 ... W0 x0
// (unchanged from round 1 — no longer the top dispatch)
// ---------------------------------------------------------------------------
#define LOAD_WF(lyr) do {                                                      \
  _Pragma("unroll") for (int kc_ = 0; kc_ < 2; ++kc_) {                        \
    const int aoff = (lyr) * (DD * DD) + (mrow + l16) * 64 + kc_ * 32 + quad * 8; \
    wf[kc_][0] = *(const frag8*)&Wrh[aoff];                                    \
    wf[kc_][1] = *(const frag8*)&Wrl[aoff];                                    \
    wf[kc_][2] = *(const frag8*)&Wih[aoff];                                    \
    wf[kc_][3] = *(const frag8*)&Wil[aoff];                                    \
  }                                                                            \
} while (0)

#define PREFETCH_X(lyr) do {                                                   \
  const float* xr_ = x_r + ((size_t)b * NL + (lyr)) * (DD * DD);               \
  const float* xi_ = x_i + ((size_t)b * NL + (lyr)) * (DD * DD);               \
  _Pragma("unroll") for (int kc_ = 0; kc_ < 2; ++kc_) {                        \
    const int aoff = (mrow + l16) * 64 + kc_ * 32 + quad * 8;                  \
    xr4[kc_][0] = *(const float4*)(xr_ + aoff);                                \
    xr4[kc_][1] = *(const float4*)(xr_ + aoff + 4);                            \
    xr4[kc_][2] = *(const float4*)(xi_ + aoff);                                \
    xr4[kc_][3] = *(const float4*)(xi_ + aoff + 4);                            \
  }                                                                            \
} while (0)

#define CONV_X() do {                                                          \
  _Pragma("unroll") for (int kc_ = 0; kc_ < 2; ++kc_) {                        \
    conv_split(xr4[kc_][0], xr4[kc_][1], xf[kc_][0], xf[kc_][1]);              \
    conv_split(xr4[kc_][2], xr4[kc_][3], xf[kc_][2], xf[kc_][3]);              \
  }                                                                            \
} while (0)

#define CMM_FR(f, rb) do {                                                     \
  _Pragma("unroll") for (int c = 0; c < 4; ++c) { accr[c] = zero4; acci[c] = zero4; } \
  _Pragma("unroll") for (int kc = 0; kc < 2; ++kc) {                           \
    const int k0 = kc * 32 + quad * 8;                                         \
    const frag8 arh = f[kc][0], arl = f[kc][1];                                \
    const frag8 aih = f[kc][2], ail = f[kc][3];                                \
    const frag8 aihn = aih ^ (short)0x8000;                                    \
    const frag8 ailn = ail ^ (short)0x8000;                                    \
    _Pragma("unroll") for (int c = 0; c < 4; ++c) {                            \
      const int bi = (c * 16 + l16) * 64 + (k0 ^ ((l16 & 7) * 8));             \
      frag8 brh = *(const frag8*)&B_rh[rb][bi];                                \
      frag8 brl = *(const frag8*)&B_rl[rb][bi];                                \
      frag8 bih = *(const frag8*)&B_ih[rb][bi];                                \
      frag8 bil = *(const frag8*)&B_il[rb][bi];                                \
      accr[c] = MFMA16(arh,  brh, accr[c]);                                    \
      accr[c] = MFMA16(arh,  brl, accr[c]);                                    \
      accr[c] = MFMA16(arl,  brh, accr[c]);                                    \
      accr[c] = MFMA16(aihn, bih, accr[c]);                                    \
      accr[c] = MFMA16(aihn, bil, accr[c]);                                    \
      accr[c] = MFMA16(ailn, bih, accr[c]);                                    \
      acci[c] = MFMA16(arh,  bih, acci[c]);                                    \
      acci[c] = MFMA16(arh,  bil, acci[c]);                                    \
      acci[c] = MFMA16(arl,  bih, acci[c]);                                    \
      acci[c] = MFMA16(aih,  brh, acci[c]);                                    \
      acci[c] = MFMA16(aih,  brl, acci[c]);                                    \
      acci[c] = MFMA16(ail,  brh, acci[c]);                                    \
    }                                                                          \
  }                                                                            \
} while (0)

#define WRITE_BT(wb) do {                                                      \
  _Pragma("unroll") for (int c = 0; c < 4; ++c) {                              \
    const int wi = (c * 16 + l16) * 64 + ((mrow + quad * 4) ^ ((l16 & 7) * 8)); \
    s16x4 rh, rl, ih, il;                                                      \
    _Pragma("unroll") for (int g = 0; g < 4; ++g) {                            \
      short h_, l_;                                                            \
      split2(accr[c][g], h_, l_); rh[g] = h_; rl[g] = l_;                      \
      split2(acci[c][g], h_, l_); ih[g] = h_; il[g] = l_;                      \
    }                                                                          \
    *(s16x4*)&B_rh[wb][wi] = rh;                                               \
    *(s16x4*)&B_rl[wb][wi] = rl;                                               \
    *(s16x4*)&B_ih[wb][wi] = ih;                                               \
    *(s16x4*)&B_il[wb][wi] = il;                                               \
  }                                                                            \
} while (0)

__global__ __launch_bounds__(256, 2) void chain_kernel(
    const float* __restrict__ x_r, const float* __restrict__ x_i,
    const float* __restrict__ u_r, const float* __restrict__ u_i,
    const unsigned short* __restrict__ Wsp,
    unsigned short* __restrict__ feat)
{
  __shared__ short B_rh[2][DD * DD];    // 4 arrays x 2 bufs x 8 KB = 64 KB
  __shared__ short B_rl[2][DD * DD];
  __shared__ short B_ih[2][DD * DD];
  __shared__ short B_il[2][DD * DD];

  const int tid  = threadIdx.x;
  const int b    = blockIdx.x;
  const int lane = tid & 63;
  const int quad = lane >> 4;
  const int l16  = lane & 15;
  const int mrow = (tid >> 6) * 16;
  const f32x4 zero4 = {0.f, 0.f, 0.f, 0.f};
  f32x4 accr[4], acci[4];

  const short* Wrh = (const short*)Wsp;
  const short* Wrl = Wrh + NL * DD * DD;
  const short* Wih = Wrl + NL * DD * DD;
  const short* Wil = Wih + NL * DD * DD;

  frag8  wf[2][4];    // next W-phase fragments (prefetched)
  float4 xr4[2][4];   // next x-phase raw floats (prefetched)
  frag8  xf[2][4];    // converted x fragments (phase-local)

  // stage x0 transposed into buf 0
  {
    const float* xr0 = x_r + (size_t)b * (NL * DD * DD);
    const float* xi0 = x_i + (size_t)b * (NL * DD * DD);
    _Pragma("unroll")
    for (int j = 0; j < 16; ++j) {
      const int idx = j * 256 + tid;
      const int q = idx >> 6, r = idx & 63;
      const int w = r * 64 + (q ^ ((r & 7) * 8));
      short h_, l_;
      split2(xr0[idx], h_, l_); B_rh[0][w] = h_; B_rl[0][w] = l_;
      split2(xi0[idx], h_, l_); B_ih[0][w] = h_; B_il[0][w] = l_;
    }
  }
  LOAD_WF(0);          // prologue: W0 fragments (latency paid once)
  __syncthreads();

  int pb = 0;
  _Pragma("unroll 1")
  for (int step = 0; step < 7; ++step) {
    // phase A: tmp = W[step] * out    (reads buf pb, writes pb^1)
    PREFETCH_X(step + 1);             // issue x loads; land during MFMAs
    CMM_FR(wf, pb);
    WRITE_BT(pb ^ 1);
    __syncthreads();
    pb ^= 1;
    // phase B: out = x[step+1] * tmp
    CONV_X();                         // x floats arrived one phase ago
    LOAD_WF(step + 1);                // issue next W frag loads
    CMM_FR(xf, pb);
    WRITE_BT(pb ^ 1);
    __syncthreads();
    pb ^= 1;
  }
  // final: acc = W7 * out
  CMM_FR(wf, pb);

  const float* ur = u_r + (size_t)b * (DD * DD);
  const float* ui = u_i + (size_t)b * (DD * DD);
  unsigned short* fb = feat + (size_t)b * HIN;
  _Pragma("unroll")
  for (int c = 0; c < 4; ++c) {
    _Pragma("unroll")
    for (int g = 0; g < 4; ++g) {
      const int p = mrow + quad * 4 + g;
      const int r = c * 16 + l16;
      fb[p * 128 + r]      = f2bf(ur[p * 64 + r] - accr[c][g]);
      fb[p * 128 + 64 + r] = f2bf(ui[p * 64 + r] - acci[c][g]);
    }
  }
}

// ---------------------------------------------------------------------------
// Split-K GEMM, v3: software-pipelined K-loop (prefetch depth 1, counted
// vmcnt — never 0 in steady state). A: global_load_lds into double-buffered
// As[2] (16 KB each). B: reg-staged fp32 -> v_perm RTZ bf16 -> ds_write into
// single 16 KB Bs (write(t) happens after barrier proving reads(t-1) done).
// LDS total 48 KB. Raw s_barrier + inline-asm waits keep next-tile loads in
// flight across barriers. Atomic fp32 accumulate into single part buffer.
// ---------------------------------------------------------------------------
__global__ __launch_bounds__(256, 2) void gemm_splitk_kernel(
    const unsigned short* __restrict__ A,
    const float* __restrict__ Wg,
    float* __restrict__ part,
    const int K, const int S)
{
  __shared__ __align__(16) short As[2][128 * 64];  // 2 x 16 KB, idx=r*64+(c^((r&7)*8))
  __shared__ __align__(16) short Bs[128 * 64];     // 16 KB bf16, same swizzle

  const int tid = threadIdx.x;
  const int bx  = blockIdx.x;
  // decode: xcd = bx&7; j = bx>>3 = m + 4*(s + S*n_sub)  (m fastest => same-B blocks adjacent)
  const int jj     = bx >> 3;
  const int m_tile = jj & 3;
  const int t2     = jj >> 2;
  const int s      = t2 % S;
  const int n_sub  = t2 / S;
  const int n_tile = (bx & 7) * 4 + n_sub;
  const int m0 = m_tile * 128, n0 = n_tile * 128;
  const int kPer  = K / S;
  const int kBase = s * kPer;

  const int wv = tid >> 6, lane = tid & 63;
  const int quad = lane >> 4, l16 = lane & 15;
  const int wm = wv & 1, wn = wv >> 1;

  // --- A staging (GLL, pre-swizzled global source, linear LDS dest) --------
  const int arow_loc = lane >> 3;
  const int acol     = ((lane & 7) ^ arow_loc) * 8;
  const unsigned short* aG[4];
  int aLoff[4];                              // wave-uniform short offsets
  _Pragma("unroll")
  for (int t = 0; t < 4; ++t) {
    const int r = 32 * wv + 8 * t + arow_loc;
    aG[t]    = A + (size_t)(m0 + r) * K + kBase + acol;
    aLoff[t] = (32 * wv + 8 * t) * 64;
  }
  // --- B staging (reg): linear global read, swizzled ds_write --------------
  const int brow_loc = lane >> 4;            // 0..3
  const int cg       = lane & 15;            // col-group (4 floats)
  const float* bG[8];
  int bW[8];                                 // short-index for ds_write_b64
  _Pragma("unroll")
  for (int t = 0; t < 8; ++t) {
    const int r = 32 * wv + 4 * t + brow_loc;
    bG[t] = Wg + (size_t)(n0 + r) * K + kBase + cg * 4;
    bW[t] = r * 64 + (((cg >> 1) ^ (r & 7)) << 3) + (cg & 1) * 4;
  }

#define ISSUE_AB(nbuf, breg) do {                                              \
  _Pragma("unroll") for (int t = 0; t < 4; ++t) {                              \
    GLL16(aG[t], &As[nbuf][aLoff[t]]); aG[t] += 64; }                          \
  _Pragma("unroll") for (int t = 0; t < 8; ++t) {                              \
    breg[t] = *(const f32x4*)bG[t]; bG[t] += 64; }                             \
} while (0)

#define WRITE_BS(breg) do {                                                    \
  _Pragma("unroll") for (int t = 0; t < 8; ++t) {                              \
    union { s16x4 v; unsigned u[2]; } w_;                                      \
    w_.u[0] = __builtin_amdgcn_perm(__float_as_uint(breg[t][1]),               \
                                    __float_as_uint(breg[t][0]), 0x07060302u); \
    w_.u[1] = __builtin_amdgcn_perm(__float_as_uint(breg[t][3]),               \
                                    __float_as_uint(breg[t][2]), 0x07060302u); \
    *(s16x4*)&Bs[bW[t]] = w_.v; }                                              \
} while (0)

#define GCOMPUTE(cbuf) do {                                                    \
  __builtin_amdgcn_s_setprio(1);                                               \
  _Pragma("unroll") for (int kc = 0; kc < 2; ++kc) {                           \
    const int k0 = kc * 32 + quad * 8;                                         \
    const int swz = (l16 & 7) * 8;                                             \
    frag8 af[4];                                                               \
    _Pragma("unroll") for (int i = 0; i < 4; ++i) {                            \
      const int r = wm * 64 + i * 16 + l16;                                    \
      af[i] = *(const frag8*)&As[cbuf][r * 64 + (k0 ^ swz)];                   \
    }                                                                          \
    _Pragma("unroll") for (int j = 0; j < 4; ++j) {                            \
      const int r = wn * 64 + j * 16 + l16;                                    \
      const frag8 bf = *(const frag8*)&Bs[r * 64 + (k0 ^ swz)];                \
      _Pragma("unroll") for (int i = 0; i < 4; ++i)                            \
        acc[i][j] = MFMA16(af[i], bf, acc[i][j]);                              \
    }                                                                          \
  }                                                                            \
  __builtin_amdgcn_s_setprio(0);                                               \
} while (0)

  const f32x4 zero4 = {0.f, 0.f, 0.f, 0.f};
  f32x4 acc[4][4];
  _Pragma("unroll")
  for (int i = 0; i < 4; ++i)
    _Pragma("unroll")
    for (int j = 0; j < 4; ++j) acc[i][j] = zero4;

  f32x4 b1[8], b2[8];
  const int kIters = kPer >> 6;              // 32 (gemm1) / 16 (gemm2), even

  ISSUE_AB(0, b1);                           // prologue: tile 0 in flight
  __syncthreads();                           // (also covers any LDS init races)

  _Pragma("unroll 1")
  for (int kt = 0; kt < kIters; kt += 2) {
    // ---- even sub-step: tile kt from As[0]/b1; prefetch kt+1 -------------
    ISSUE_AB(1, b2);                         // 12 more in flight (24 total)
    VMW(12);                                 // tile kt's 12 loads done
    WRITE_BS(b1);                            // Bs(kt); reads(kt-1) done at last BAR
    LGW();
    BAR();                                   // As[0]+Bs complete across waves
    GCOMPUTE(0);
    BAR();                                   // all waves done reading As[0],Bs
    // ---- odd sub-step: tile kt+1 from As[1]/b2; prefetch kt+2 ------------
    if (kt + 2 < kIters) { ISSUE_AB(0, b1); VMW(12); }
    else                 { VMW(0); }
    WRITE_BS(b2);
    LGW();
    BAR();
    GCOMPUTE(1);
    BAR();
  }

#undef ISSUE_AB
#undef WRITE_BS
#undef GCOMPUTE

  // accumulate fp32 partials into the single part buffer (device-scope atomics)
  _Pragma("unroll")
  for (int i = 0; i < 4; ++i) {
    _Pragma("unroll")
    for (int j = 0; j < 4; ++j) {
      const int n = n0 + wn * 64 + j * 16 + l16;
      _Pragma("unroll")
      for (int g = 0; g < 4; ++g) {
        const int m = m0 + wm * 64 + i * 16 + quad * 4 + g;
        atomicAdd(&part[(size_t)m * HIDN + n], acc[i][j][g]);
      }
    }
  }
}

// ---------------------------------------------------------------------------
// Zero the partial buffer (runs once per launch, ~1.5 us)
// ---------------------------------------------------------------------------
__global__ __launch_bounds__(256) void zero_kernel(float* __restrict__ p) {
  const int idx4 = (blockIdx.x * 256 + threadIdx.x) * 4;
  const f32x4 z = {0.f, 0.f, 0.f, 0.f};
  *(f32x4*)&p[idx4] = z;
}

// ---------------------------------------------------------------------------
// bias + mish -> bf16, and re-zero part for the next GEMM
// ---------------------------------------------------------------------------
__global__ __launch_bounds__(256) void reduce_mish_kernel(
    float* __restrict__ part, const float* __restrict__ bias,
    unsigned short* __restrict__ outp)
{
  const int idx4 = (blockIdx.x * 256 + threadIdx.x) * 4;   // < 512*4096
  const int n = idx4 & (HIDN - 1);
  f32x4 acc = *(const f32x4*)&part[idx4];
  const f32x4 z = {0.f, 0.f, 0.f, 0.f};
  *(f32x4*)&part[idx4] = z;
  const f32x4 bv = *(const f32x4*)&bias[n];
  s16x4 o;
  _Pragma("unroll")
  for (int g = 0; g < 4; ++g) o[g] = (short)f2bf(mish_f(acc[g] + bv[g]));
  *(s16x4*)&outp[idx4] = o;
}

// ---------------------------------------------------------------------------
// Final gemv: out[b] = sum_k h2[b][k]*w3[k] + b3
// ---------------------------------------------------------------------------
__global__ __launch_bounds__(256) void gemv_kernel(
    const unsigned short* __restrict__ h2,
    const float* __restrict__ w3,
    const float* __restrict__ b3,
    float* __restrict__ outp)
{
  const int gw   = (int)((blockIdx.x * 256 + threadIdx.x) >> 6);
  const int lane = threadIdx.x & 63;
  const unsigned short* hp = h2 + (size_t)gw * HIDN;
  float s = 0.f;
  for (int j = 0; j < 16; ++j) {
    const int k = j * 256 + lane * 4;
    const s16x4 h = *(const s16x4*)(hp + k);
    const float4 w = *(const float4*)(w3 + k);
    s += bf2f((unsigned short)h[0]) * w.x + bf2f((unsigned short)h[1]) * w.y
       + bf2f((unsigned short)h[2]) * w.z + bf2f((unsigned short)h[3]) * w.w;
  }
  _Pragma("unroll")
  for (int off = 32; off > 0; off >>= 1) s += __shfl_down(s, off, 64);
  if (lane == 0) outp[gw] = s + b3[0];
}

extern "C" void kernel_launch(void* const* d_in, const int* in_sizes, int n_in,
                              void* d_out, int out_size, void* d_ws, size_t ws_size,
                              hipStream_t stream) {
  const float* x_r = (const float*)d_in[0];
  const float* x_i = (const float*)d_in[1];
  const float* u_r = (const float*)d_in[2];
  const float* u_i = (const float*)d_in[3];
  const float* W_r = (const float*)d_in[4];
  const float* W_i = (const float*)d_in[5];
  const float* w1  = (const float*)d_in[6];
  const float* b1  = (const float*)d_in[7];
  const float* w2  = (const float*)d_in[8];
  const float* b2  = (const float*)d_in[9];
  const float* w3  = (const float*)d_in[10];
  const float* b3  = (const float*)d_in[11];
  float* out = (float*)d_out;

  unsigned short* feat = (unsigned short*)d_ws;             // 512*8192 bf16 = 8 MB
  unsigned short* h1   = feat + (size_t)MM * HIN;           // 4 MB
  unsigned short* h2   = h1 + (size_t)MM * HIDN;            // 4 MB
  float* part = (float*)(h2 + (size_t)MM * HIDN);           // 8.39 MB fp32 (single)
  unsigned short* Wsp = h1;   // W hi/lo split lives in h1 region (256 KB),
                              // dead before reduce_mish writes h1

  w_split_kernel<<<128, 256, 0, stream>>>(W_r, W_i, Wsp);
  zero_kernel<<<2048, 256, 0, stream>>>(part);
  chain_kernel<<<512, 256, 0, stream>>>(x_r, x_i, u_r, u_i, Wsp, feat);
  gemm_splitk_kernel<<<128 * SPLITS, 256, 0, stream>>>(feat, w1, part, HIN, SPLITS);
  reduce_mish_kernel<<<2048, 256, 0, stream>>>(part, b1, h1);
  gemm_splitk_kernel<<<128 * SPLITS, 256, 0, stream>>>(h1, w2, part, HIDN, SPLITS);
  reduce_mish_kernel<<<2048, 256, 0, stream>>>(part, b2, h2);
  gemv_kernel<<<128, 256, 0, stream>>>(h2, w3, b3, out);
}

// Round 3
// 442.344 us; speedup vs baseline: 1.0682x; 1.0449x over previous
//
#include <hip/hip_runtime.h>

#define NL     8
#define DD     64
#define HIN    8192
#define HIDN   4096
#define MM     512
#define SPLITS 4

using frag8 = __attribute__((ext_vector_type(8))) short;   // 8 bf16 (4 VGPRs)
using f32x4 = __attribute__((ext_vector_type(4))) float;
using s16x4 = __attribute__((ext_vector_type(4))) short;

#define MFMA16(a, b, c) __builtin_amdgcn_mfma_f32_16x16x32_bf16((a), (b), (c), 0, 0, 0)

// global -> LDS direct DMA, 16 B per lane. LDS dest = wave-uniform base + lane*16.
#define GLL16(g, l)                                                            \
  __builtin_amdgcn_global_load_lds(                                            \
      (const __attribute__((address_space(1))) void*)(g),                      \
      (__attribute__((address_space(3))) void*)(l), 16, 0, 0)

// pipelining fences (rule #18: sched_barrier after inline-asm waits/barriers)
#define VMW(n) do { asm volatile("s_waitcnt vmcnt(" #n ")" ::: "memory");      \
                    __builtin_amdgcn_sched_barrier(0); } while (0)
#define LGW()  do { asm volatile("s_waitcnt lgkmcnt(0)" ::: "memory");         \
                    __builtin_amdgcn_sched_barrier(0); } while (0)
#define BAR()  do { __builtin_amdgcn_s_barrier();                              \
                    __builtin_amdgcn_sched_barrier(0); } while (0)

static __device__ __forceinline__ float bf2f(unsigned short h) {
  union { unsigned u; float f; } c; c.u = ((unsigned)h) << 16; return c.f;
}
static __device__ __forceinline__ unsigned short f2bf(float f) {
  union { float f; unsigned u; } c; c.f = f;
  unsigned u = c.u + 0x7FFFu + ((c.u >> 16) & 1u);   // RNE
  return (unsigned short)(u >> 16);
}
static __device__ __forceinline__ void split2(float v, short& hi, short& lo) {
  unsigned short h = f2bf(v);
  hi = (short)h;
  lo = (short)f2bf(v - bf2f(h));
}
// convert 8 fp32 (already in regs) -> hi/lo bf16 frags
static __device__ __forceinline__ void conv_split(const float4 v0, const float4 v1,
                                                  frag8& hi, frag8& lo) {
  float vv[8] = {v0.x, v0.y, v0.z, v0.w, v1.x, v1.y, v1.z, v1.w};
  _Pragma("unroll")
  for (int t = 0; t < 8; ++t) {
    unsigned short h = f2bf(vv[t]);
    hi[t] = (short)h;
    lo[t] = (short)f2bf(vv[t] - bf2f(h));
  }
}

static __device__ __forceinline__ float mish_f(float x) {
  float e  = __expf(x);
  float sp = (x > 15.f) ? x : __logf(1.f + e);      // softplus, stable for huge |x|
  float em = __expf(-2.f * sp);
  float t  = (1.f - em) / (1.f + em);               // tanh(sp), sp>=0
  return x * t;
}

// ---------------------------------------------------------------------------
// Pre-split W (8 x 64 x 64 complex) into bf16 hi/lo once.
// Layout: Wsp = [rh | rl | ih | il], each NL*DD*DD shorts.
// ---------------------------------------------------------------------------
__global__ __launch_bounds__(256) void w_split_kernel(
    const float* __restrict__ W_r, const float* __restrict__ W_i,
    unsigned short* __restrict__ Wsp)
{
  const int idx = blockIdx.x * 256 + threadIdx.x;   // < NL*DD*DD = 32768
  short h, l;
  split2(W_r[idx], h, l);
  Wsp[idx]             = (unsigned short)h;
  Wsp[32768 + idx]     = (unsigned short)l;
  split2(W_i[idx], h, l);
  Wsp[2 * 32768 + idx] = (unsigned short)h;
  Wsp[3 * 32768 + idx] = (unsigned short)l;
}

// ---------------------------------------------------------------------------
// Kernel 1: per-batch matrix chain  out = u - W7 x7 W6 x6 ... W0 x0
// (unchanged this round — re-attack once it tops the profile again)
// ---------------------------------------------------------------------------
#define LOAD_WF(lyr) do {                                                      \
  _Pragma("unroll") for (int kc_ = 0; kc_ < 2; ++kc_) {                        \
    const int aoff = (lyr) * (DD * DD) + (mrow + l16) * 64 + kc_ * 32 + quad * 8; \
    wf[kc_][0] = *(const frag8*)&Wrh[aoff];                                    \
    wf[kc_][1] = *(const frag8*)&Wrl[aoff];                                    \
    wf[kc_][2] = *(const frag8*)&Wih[aoff];                                    \
    wf[kc_][3] = *(const frag8*)&Wil[aoff];                                    \
  }                                                                            \
} while (0)

#define PREFETCH_X(lyr) do {                                                   \
  const float* xr_ = x_r + ((size_t)b * NL + (lyr)) * (DD * DD);               \
  const float* xi_ = x_i + ((size_t)b * NL + (lyr)) * (DD * DD);               \
  _Pragma("unroll") for (int kc_ = 0; kc_ < 2; ++kc_) {                        \
    const int aoff = (mrow + l16) * 64 + kc_ * 32 + quad * 8;                  \
    xr4[kc_][0] = *(const float4*)(xr_ + aoff);                                \
    xr4[kc_][1] = *(const float4*)(xr_ + aoff + 4);                            \
    xr4[kc_][2] = *(const float4*)(xi_ + aoff);                                \
    xr4[kc_][3] = *(const float4*)(xi_ + aoff + 4);                            \
  }                                                                            \
} while (0)

#define CONV_X() do {                                                          \
  _Pragma("unroll") for (int kc_ = 0; kc_ < 2; ++kc_) {                        \
    conv_split(xr4[kc_][0], xr4[kc_][1], xf[kc_][0], xf[kc_][1]);              \
    conv_split(xr4[kc_][2], xr4[kc_][3], xf[kc_][2], xf[kc_][3]);              \
  }                                                                            \
} while (0)

#define CMM_FR(f, rb) do {                                                     \
  _Pragma("unroll") for (int c = 0; c < 4; ++c) { accr[c] = zero4; acci[c] = zero4; } \
  _Pragma("unroll") for (int kc = 0; kc < 2; ++kc) {                           \
    const int k0 = kc * 32 + quad * 8;                                         \
    const frag8 arh = f[kc][0], arl = f[kc][1];                                \
    const frag8 aih = f[kc][2], ail = f[kc][3];                                \
    const frag8 aihn = aih ^ (short)0x8000;                                    \
    const frag8 ailn = ail ^ (short)0x8000;                                    \
    _Pragma("unroll") for (int c = 0; c < 4; ++c) {                            \
      const int bi = (c * 16 + l16) * 64 + (k0 ^ ((l16 & 7) * 8));             \
      frag8 brh = *(const frag8*)&B_rh[rb][bi];                                \
      frag8 brl = *(const frag8*)&B_rl[rb][bi];                                \
      frag8 bih = *(const frag8*)&B_ih[rb][bi];                                \
      frag8 bil = *(const frag8*)&B_il[rb][bi];                                \
      accr[c] = MFMA16(arh,  brh, accr[c]);                                    \
      accr[c] = MFMA16(arh,  brl, accr[c]);                                    \
      accr[c] = MFMA16(arl,  brh, accr[c]);                                    \
      accr[c] = MFMA16(aihn, bih, accr[c]);                                    \
      accr[c] = MFMA16(aihn, bil, accr[c]);                                    \
      accr[c] = MFMA16(ailn, bih, accr[c]);                                    \
      acci[c] = MFMA16(arh,  bih, acci[c]);                                    \
      acci[c] = MFMA16(arh,  bil, acci[c]);                                    \
      acci[c] = MFMA16(arl,  bih, acci[c]);                                    \
      acci[c] = MFMA16(aih,  brh, acci[c]);                                    \
      acci[c] = MFMA16(aih,  brl, acci[c]);                                    \
      acci[c] = MFMA16(ail,  brh, acci[c]);                                    \
    }                                                                          \
  }                                                                            \
} while (0)

#define WRITE_BT(wb) do {                                                      \
  _Pragma("unroll") for (int c = 0; c < 4; ++c) {                              \
    const int wi = (c * 16 + l16) * 64 + ((mrow + quad * 4) ^ ((l16 & 7) * 8)); \
    s16x4 rh, rl, ih, il;                                                      \
    _Pragma("unroll") for (int g = 0; g < 4; ++g) {                            \
      short h_, l_;                                                            \
      split2(accr[c][g], h_, l_); rh[g] = h_; rl[g] = l_;                      \
      split2(acci[c][g], h_, l_); ih[g] = h_; il[g] = l_;                      \
    }                                                                          \
    *(s16x4*)&B_rh[wb][wi] = rh;                                               \
    *(s16x4*)&B_rl[wb][wi] = rl;                                               \
    *(s16x4*)&B_ih[wb][wi] = ih;                                               \
    *(s16x4*)&B_il[wb][wi] = il;                                               \
  }                                                                            \
} while (0)

__global__ __launch_bounds__(256, 2) void chain_kernel(
    const float* __restrict__ x_r, const float* __restrict__ x_i,
    const float* __restrict__ u_r, const float* __restrict__ u_i,
    const unsigned short* __restrict__ Wsp,
    unsigned short* __restrict__ feat)
{
  __shared__ short B_rh[2][DD * DD];    // 4 arrays x 2 bufs x 8 KB = 64 KB
  __shared__ short B_rl[2][DD * DD];
  __shared__ short B_ih[2][DD * DD];
  __shared__ short B_il[2][DD * DD];

  const int tid  = threadIdx.x;
  const int b    = blockIdx.x;
  const int lane = tid & 63;
  const int quad = lane >> 4;
  const int l16  = lane & 15;
  const int mrow = (tid >> 6) * 16;
  const f32x4 zero4 = {0.f, 0.f, 0.f, 0.f};
  f32x4 accr[4], acci[4];

  const short* Wrh = (const short*)Wsp;
  const short* Wrl = Wrh + NL * DD * DD;
  const short* Wih = Wrl + NL * DD * DD;
  const short* Wil = Wih + NL * DD * DD;

  frag8  wf[2][4];    // next W-phase fragments (prefetched)
  float4 xr4[2][4];   // next x-phase raw floats (prefetched)
  frag8  xf[2][4];    // converted x fragments (phase-local)

  // stage x0 transposed into buf 0
  {
    const float* xr0 = x_r + (size_t)b * (NL * DD * DD);
    const float* xi0 = x_i + (size_t)b * (NL * DD * DD);
    _Pragma("unroll")
    for (int j = 0; j < 16; ++j) {
      const int idx = j * 256 + tid;
      const int q = idx >> 6, r = idx & 63;
      const int w = r * 64 + (q ^ ((r & 7) * 8));
      short h_, l_;
      split2(xr0[idx], h_, l_); B_rh[0][w] = h_; B_rl[0][w] = l_;
      split2(xi0[idx], h_, l_); B_ih[0][w] = h_; B_il[0][w] = l_;
    }
  }
  LOAD_WF(0);          // prologue: W0 fragments (latency paid once)
  __syncthreads();

  int pb = 0;
  _Pragma("unroll 1")
  for (int step = 0; step < 7; ++step) {
    // phase A: tmp = W[step] * out    (reads buf pb, writes pb^1)
    PREFETCH_X(step + 1);             // issue x loads; land during MFMAs
    CMM_FR(wf, pb);
    WRITE_BT(pb ^ 1);
    __syncthreads();
    pb ^= 1;
    // phase B: out = x[step+1] * tmp
    CONV_X();                         // x floats arrived one phase ago
    LOAD_WF(step + 1);                // issue next W frag loads
    CMM_FR(xf, pb);
    WRITE_BT(pb ^ 1);
    __syncthreads();
    pb ^= 1;
  }
  // final: acc = W7 * out
  CMM_FR(wf, pb);

  const float* ur = u_r + (size_t)b * (DD * DD);
  const float* ui = u_i + (size_t)b * (DD * DD);
  unsigned short* fb = feat + (size_t)b * HIN;
  _Pragma("unroll")
  for (int c = 0; c < 4; ++c) {
    _Pragma("unroll")
    for (int g = 0; g < 4; ++g) {
      const int p = mrow + quad * 4 + g;
      const int r = c * 16 + l16;
      fb[p * 128 + r]      = f2bf(ur[p * 64 + r] - accr[c][g]);
      fb[p * 128 + 64 + r] = f2bf(ui[p * 64 + r] - acci[c][g]);
    }
  }
}

// ---------------------------------------------------------------------------
// Split-K GEMM, v4: same pipelined K-loop as v3; epilogue now writes PLAIN
// coalesced fp32 stores to a per-split part buffer (part + s*MM*HIDN) when
// the workspace fits S buffers, eliminating 8.4M serialized L2 atomic RMWs.
// Atomic single-buffer path kept as fallback (useAtomic=1).
// ---------------------------------------------------------------------------
__global__ __launch_bounds__(256, 2) void gemm_splitk_kernel(
    const unsigned short* __restrict__ A,
    const float* __restrict__ Wg,
    float* __restrict__ part,
    const int K, const int S, const int useAtomic)
{
  __shared__ __align__(16) short As[2][128 * 64];  // 2 x 16 KB, idx=r*64+(c^((r&7)*8))
  __shared__ __align__(16) short Bs[128 * 64];     // 16 KB bf16, same swizzle

  const int tid = threadIdx.x;
  const int bx  = blockIdx.x;
  // decode: xcd = bx&7; j = bx>>3 = m + 4*(s + S*n_sub)  (m fastest => same-B blocks adjacent)
  const int jj     = bx >> 3;
  const int m_tile = jj & 3;
  const int t2     = jj >> 2;
  const int s      = t2 % S;
  const int n_sub  = t2 / S;
  const int n_tile = (bx & 7) * 4 + n_sub;
  const int m0 = m_tile * 128, n0 = n_tile * 128;
  const int kPer  = K / S;
  const int kBase = s * kPer;

  const int wv = tid >> 6, lane = tid & 63;
  const int quad = lane >> 4, l16 = lane & 15;
  const int wm = wv & 1, wn = wv >> 1;

  // --- A staging (GLL, pre-swizzled global source, linear LDS dest) --------
  const int arow_loc = lane >> 3;
  const int acol     = ((lane & 7) ^ arow_loc) * 8;
  const unsigned short* aG[4];
  int aLoff[4];                              // wave-uniform short offsets
  _Pragma("unroll")
  for (int t = 0; t < 4; ++t) {
    const int r = 32 * wv + 8 * t + arow_loc;
    aG[t]    = A + (size_t)(m0 + r) * K + kBase + acol;
    aLoff[t] = (32 * wv + 8 * t) * 64;
  }
  // --- B staging (reg): linear global read, swizzled ds_write --------------
  const int brow_loc = lane >> 4;            // 0..3
  const int cg       = lane & 15;            // col-group (4 floats)
  const float* bG[8];
  int bW[8];                                 // short-index for ds_write_b64
  _Pragma("unroll")
  for (int t = 0; t < 8; ++t) {
    const int r = 32 * wv + 4 * t + brow_loc;
    bG[t] = Wg + (size_t)(n0 + r) * K + kBase + cg * 4;
    bW[t] = r * 64 + (((cg >> 1) ^ (r & 7)) << 3) + (cg & 1) * 4;
  }

#define ISSUE_AB(nbuf, breg) do {                                              \
  _Pragma("unroll") for (int t = 0; t < 4; ++t) {                              \
    GLL16(aG[t], &As[nbuf][aLoff[t]]); aG[t] += 64; }                          \
  _Pragma("unroll") for (int t = 0; t < 8; ++t) {                              \
    breg[t] = *(const f32x4*)bG[t]; bG[t] += 64; }                             \
} while (0)

#define WRITE_BS(breg) do {                                                    \
  _Pragma("unroll") for (int t = 0; t < 8; ++t) {                              \
    union { s16x4 v; unsigned u[2]; } w_;                                      \
    w_.u[0] = __builtin_amdgcn_perm(__float_as_uint(breg[t][1]),               \
                                    __float_as_uint(breg[t][0]), 0x07060302u); \
    w_.u[1] = __builtin_amdgcn_perm(__float_as_uint(breg[t][3]),               \
                                    __float_as_uint(breg[t][2]), 0x07060302u); \
    *(s16x4*)&Bs[bW[t]] = w_.v; }                                              \
} while (0)

#define GCOMPUTE(cbuf) do {                                                    \
  __builtin_amdgcn_s_setprio(1);                                               \
  _Pragma("unroll") for (int kc = 0; kc < 2; ++kc) {                           \
    const int k0 = kc * 32 + quad * 8;                                         \
    const int swz = (l16 & 7) * 8;                                             \
    frag8 af[4];                                                               \
    _Pragma("unroll") for (int i = 0; i < 4; ++i) {                            \
      const int r = wm * 64 + i * 16 + l16;                                    \
      af[i] = *(const frag8*)&As[cbuf][r * 64 + (k0 ^ swz)];                   \
    }                                                                          \
    _Pragma("unroll") for (int j = 0; j < 4; ++j) {                            \
      const int r = wn * 64 + j * 16 + l16;                                    \
      const frag8 bf = *(const frag8*)&Bs[r * 64 + (k0 ^ swz)];                \
      _Pragma("unroll") for (int i = 0; i < 4; ++i)                            \
        acc[i][j] = MFMA16(af[i], bf, acc[i][j]);                              \
    }                                                                          \
  }                                                                            \
  __builtin_amdgcn_s_setprio(0);                                               \
} while (0)

  const f32x4 zero4 = {0.f, 0.f, 0.f, 0.f};
  f32x4 acc[4][4];
  _Pragma("unroll")
  for (int i = 0; i < 4; ++i)
    _Pragma("unroll")
    for (int j = 0; j < 4; ++j) acc[i][j] = zero4;

  f32x4 b1[8], b2[8];
  const int kIters = kPer >> 6;              // 32/16 (S=4) or 64/32 (S=2), even

  ISSUE_AB(0, b1);                           // prologue: tile 0 in flight
  __syncthreads();                           // (also covers any LDS init races)

  _Pragma("unroll 1")
  for (int kt = 0; kt < kIters; kt += 2) {
    // ---- even sub-step: tile kt from As[0]/b1; prefetch kt+1 -------------
    ISSUE_AB(1, b2);                         // 12 more in flight (24 total)
    VMW(12);                                 // tile kt's 12 loads done
    WRITE_BS(b1);                            // Bs(kt); reads(kt-1) done at last BAR
    LGW();
    BAR();                                   // As[0]+Bs complete across waves
    GCOMPUTE(0);
    BAR();                                   // all waves done reading As[0],Bs
    // ---- odd sub-step: tile kt+1 from As[1]/b2; prefetch kt+2 ------------
    if (kt + 2 < kIters) { ISSUE_AB(0, b1); VMW(12); }
    else                 { VMW(0); }
    WRITE_BS(b2);
    LGW();
    BAR();
    GCOMPUTE(1);
    BAR();
  }

#undef ISSUE_AB
#undef WRITE_BS
#undef GCOMPUTE

  // epilogue: per-split plain stores (store mode) or atomic single-buffer
  float* pb = part + (size_t)(useAtomic ? 0 : s) * MM * HIDN;
  if (useAtomic) {
    _Pragma("unroll")
    for (int i = 0; i < 4; ++i) {
      _Pragma("unroll")
      for (int j = 0; j < 4; ++j) {
        const int n = n0 + wn * 64 + j * 16 + l16;
        _Pragma("unroll")
        for (int g = 0; g < 4; ++g) {
          const int m = m0 + wm * 64 + i * 16 + quad * 4 + g;
          atomicAdd(&pb[(size_t)m * HIDN + n], acc[i][j][g]);
        }
      }
    }
  } else {
    _Pragma("unroll")
    for (int i = 0; i < 4; ++i) {
      _Pragma("unroll")
      for (int j = 0; j < 4; ++j) {
        const int n = n0 + wn * 64 + j * 16 + l16;
        _Pragma("unroll")
        for (int g = 0; g < 4; ++g) {
          const int m = m0 + wm * 64 + i * 16 + quad * 4 + g;
          pb[(size_t)m * HIDN + n] = acc[i][j][g];
        }
      }
    }
  }
}

// ---------------------------------------------------------------------------
// Zero the partial buffer (atomic mode only)
// ---------------------------------------------------------------------------
__global__ __launch_bounds__(256) void zero_kernel(float* __restrict__ p) {
  const int idx4 = (blockIdx.x * 256 + threadIdx.x) * 4;
  const f32x4 z = {0.f, 0.f, 0.f, 0.f};
  *(f32x4*)&p[idx4] = z;
}

// ---------------------------------------------------------------------------
// Sum nparts split buffers + bias + mish -> bf16.
// In atomic mode (nparts==1), re-zero part for the next GEMM.
// ---------------------------------------------------------------------------
__global__ __launch_bounds__(256) void reduce_mish_kernel(
    float* __restrict__ part, const float* __restrict__ bias,
    unsigned short* __restrict__ outp, const int nparts)
{
  const int idx4 = (blockIdx.x * 256 + threadIdx.x) * 4;   // < 512*4096
  const int n = idx4 & (HIDN - 1);
  f32x4 acc = *(const f32x4*)&part[idx4];
  if (nparts == 1) {
    const f32x4 z = {0.f, 0.f, 0.f, 0.f};
    *(f32x4*)&part[idx4] = z;
  } else {
    _Pragma("unroll 3")
    for (int s = 1; s < nparts; ++s)
      acc += *(const f32x4*)&part[(size_t)s * MM * HIDN + idx4];
  }
  const f32x4 bv = *(const f32x4*)&bias[n];
  s16x4 o;
  _Pragma("unroll")
  for (int g = 0; g < 4; ++g) o[g] = (short)f2bf(mish_f(acc[g] + bv[g]));
  *(s16x4*)&outp[idx4] = o;
}

// ---------------------------------------------------------------------------
// Final gemv: out[b] = sum_k h2[b][k]*w3[k] + b3
// ---------------------------------------------------------------------------
__global__ __launch_bounds__(256) void gemv_kernel(
    const unsigned short* __restrict__ h2,
    const float* __restrict__ w3,
    const float* __restrict__ b3,
    float* __restrict__ outp)
{
  const int gw   = (int)((blockIdx.x * 256 + threadIdx.x) >> 6);
  const int lane = threadIdx.x & 63;
  const unsigned short* hp = h2 + (size_t)gw * HIDN;
  float s = 0.f;
  for (int j = 0; j < 16; ++j) {
    const int k = j * 256 + lane * 4;
    const s16x4 h = *(const s16x4*)(hp + k);
    const float4 w = *(const float4*)(w3 + k);
    s += bf2f((unsigned short)h[0]) * w.x + bf2f((unsigned short)h[1]) * w.y
       + bf2f((unsigned short)h[2]) * w.z + bf2f((unsigned short)h[3]) * w.w;
  }
  _Pragma("unroll")
  for (int off = 32; off > 0; off >>= 1) s += __shfl_down(s, off, 64);
  if (lane == 0) outp[gw] = s + b3[0];
}

extern "C" void kernel_launch(void* const* d_in, const int* in_sizes, int n_in,
                              void* d_out, int out_size, void* d_ws, size_t ws_size,
                              hipStream_t stream) {
  const float* x_r = (const float*)d_in[0];
  const float* x_i = (const float*)d_in[1];
  const float* u_r = (const float*)d_in[2];
  const float* u_i = (const float*)d_in[3];
  const float* W_r = (const float*)d_in[4];
  const float* W_i = (const float*)d_in[5];
  const float* w1  = (const float*)d_in[6];
  const float* b1  = (const float*)d_in[7];
  const float* w2  = (const float*)d_in[8];
  const float* b2  = (const float*)d_in[9];
  const float* w3  = (const float*)d_in[10];
  const float* b3  = (const float*)d_in[11];
  float* out = (float*)d_out;

  unsigned short* feat = (unsigned short*)d_ws;             // 512*8192 bf16 = 8.39 MB
  unsigned short* h1   = feat + (size_t)MM * HIN;           // 4.19 MB
  unsigned short* h2   = h1 + (size_t)MM * HIDN;            // 4.19 MB
  float* part = (float*)(h2 + (size_t)MM * HIDN);           // S x 8.39 MB fp32
  unsigned short* Wsp = h1;   // W hi/lo split lives in h1 region (256 KB),
                              // dead before reduce_mish writes h1

  const size_t baseBytes = (size_t)MM * (HIN + 2 * HIDN) * 2;
  const size_t partBytes = (size_t)MM * HIDN * 4;
  int S, useAtomic;
  if (ws_size >= baseBytes + 4 * partBytes)      { S = 4; useAtomic = 0; }
  else if (ws_size >= baseBytes + 2 * partBytes) { S = 2; useAtomic = 0; }
  else                                           { S = 4; useAtomic = 1; }
  const int nparts = useAtomic ? 1 : S;

  w_split_kernel<<<128, 256, 0, stream>>>(W_r, W_i, Wsp);
  if (useAtomic) zero_kernel<<<2048, 256, 0, stream>>>(part);
  chain_kernel<<<512, 256, 0, stream>>>(x_r, x_i, u_r, u_i, Wsp, feat);
  gemm_splitk_kernel<<<128 * S, 256, 0, stream>>>(feat, w1, part, HIN, S, useAtomic);
  reduce_mish_kernel<<<2048, 256, 0, stream>>>(part, b1, h1, nparts);
  gemm_splitk_kernel<<<128 * S, 256, 0, stream>>>(h1, w2, part, HIDN, S, useAtomic);
  reduce_mish_kernel<<<2048, 256, 0, stream>>>(part, b2, h2, nparts);
  gemv_kernel<<<128, 256, 0, stream>>>(h2, w3, b3, out);
}